// Round 5
// baseline (296.443 us; speedup 1.0000x reference)
//
#include <hip/hip_runtime.h>

typedef unsigned short u16;
using bf16x8 = __attribute__((ext_vector_type(8))) __bf16;
using f32x4  = __attribute__((ext_vector_type(4))) float;
using u16x8  = __attribute__((ext_vector_type(8))) unsigned short;
using u16x4  = __attribute__((ext_vector_type(4))) unsigned short;

#define SEQ   2048
#define HID   1024
#define NHEAD 16
#define HD    64
#define BATCH 2
#define NTOK  4096   // BATCH*SEQ

__device__ __forceinline__ u16 f2bf(float f) {
  unsigned u = __builtin_bit_cast(unsigned, f);
  u += 0x7fffu + ((u >> 16) & 1u);
  return (u16)(u >> 16);
}

__device__ __forceinline__ void gld_lds16(const void* g, void* l) {
  __builtin_amdgcn_global_load_lds(
      (__attribute__((address_space(1))) void*)(__UINTPTR_TYPE__)g,
      (__attribute__((address_space(3))) void*)l, 16, 0, 0);
}

// ---------------- fp32 -> bf16 convert ----------------
__global__ __launch_bounds__(256) void cvt_kernel(const float* __restrict__ in,
                                                  u16* __restrict__ out) {
  int i = (blockIdx.x * 256 + threadIdx.x) * 4;
  float4 v = *reinterpret_cast<const float4*>(in + i);
  u16x4 o = { f2bf(v.x), f2bf(v.y), f2bf(v.z), f2bf(v.w) };
  *reinterpret_cast<u16x4*>(out + i) = o;
}

// ---------------- GEMM: C[M,N] = A[M,K] * B[N,K]^T ---------------- (unchanged)
template<bool BF16OUT>
__global__ __launch_bounds__(256) void gemm_bt(const u16* __restrict__ A,
                                               const u16* __restrict__ B,
                                               void* __restrict__ Cv,
                                               int M, int N, int K) {
  __shared__ u16 At[128 * 64];
  __shared__ u16 Bt[128 * 64];
  const int tid  = threadIdx.x;
  const int wave = tid >> 6;
  const int lane = tid & 63;
  const int g    = lane >> 4;
  const int r16  = lane & 15;
  const int wr   = wave >> 1;
  const int wc   = wave & 1;
  const int bm   = blockIdx.y;
  const int bn   = blockIdx.x;

  const u16* Ab = A + (size_t)bm * 128 * K;
  const u16* Bb = B + (size_t)bn * 128 * K;
  const int srow = lane >> 3;
  const int scol = (lane & 7) * 8;

  f32x4 acc[4][4] = {};

  for (int kt = 0; kt < K; kt += 64) {
#pragma unroll
    for (int c = 0; c < 4; ++c) {
      int seg = wave * 4 + c;
      gld_lds16(Ab + (size_t)(seg * 8 + srow) * K + kt + scol, &At[seg * 512]);
      gld_lds16(Bb + (size_t)(seg * 8 + srow) * K + kt + scol, &Bt[seg * 512]);
    }
    __syncthreads();
#pragma unroll
    for (int ko = 0; ko < 64; ko += 32) {
      bf16x8 af[4], bfr[4];
#pragma unroll
      for (int mi = 0; mi < 4; ++mi)
        af[mi] = *reinterpret_cast<const bf16x8*>(&At[(wr * 64 + mi * 16 + r16) * 64 + ko + g * 8]);
#pragma unroll
      for (int ni = 0; ni < 4; ++ni)
        bfr[ni] = *reinterpret_cast<const bf16x8*>(&Bt[(wc * 64 + ni * 16 + r16) * 64 + ko + g * 8]);
#pragma unroll
      for (int mi = 0; mi < 4; ++mi)
#pragma unroll
        for (int ni = 0; ni < 4; ++ni)
          acc[mi][ni] = __builtin_amdgcn_mfma_f32_16x16x32_bf16(af[mi], bfr[ni], acc[mi][ni], 0, 0, 0);
    }
    __syncthreads();
  }

#pragma unroll
  for (int mi = 0; mi < 4; ++mi)
#pragma unroll
    for (int ni = 0; ni < 4; ++ni) {
      int row0 = bm * 128 + wr * 64 + mi * 16 + g * 4;
      int col  = bn * 128 + wc * 64 + ni * 16 + r16;
#pragma unroll
      for (int r = 0; r < 4; ++r) {
        float v = acc[mi][ni][r];
        if (BF16OUT) ((u16*)Cv)[(size_t)(row0 + r) * N + col] = f2bf(v);
        else         ((float*)Cv)[(size_t)(row0 + r) * N + col] = v;
      }
    }
}

// ---------------- flash attention ----------------
// 1024 blocks (XCD-chunked remap), 4 waves x 16 q-rows; K-tile = 64
// Double-buffered K/V (2-phase), 1 barrier/tile, defer-max rescale (THR=8).
// LDS XOR-swizzle on 16B-chunk index: s(row)=((row>>4)+(row&7))&7
__global__ __launch_bounds__(256, 4) void attn_kernel(const u16* __restrict__ qkv,
                                                      const float* __restrict__ mask,
                                                      u16* __restrict__ AO) {
  __shared__ u16 Kt[2][64 * 64];   // [key][d]   swizzled
  __shared__ u16 Vt[2][64 * 64];   // [d][key]   swizzled (transposed)
  __shared__ u16 Pl[4][16 * 64];   // per-wave P swizzled (wave-private)

  const int tid  = threadIdx.x;
  const int w    = tid >> 6;
  const int lane = tid & 63;
  const int g    = lane >> 4;
  const int r16  = lane & 15;

  const int n  = blockIdx.x;
  const int x  = n & 7;
  const int s_ = n >> 3;
  const int h  = s_ & 15;
  const int t_ = ((s_ >> 4) << 3) + x;
  const int b  = t_ >> 5;
  const int qt = t_ & 31;

  const size_t tokbase = (size_t)b * SEQ;

  bf16x8 aq[2];
  {
    int qrow = qt * 64 + w * 16 + r16;
#pragma unroll
    for (int ko = 0; ko < 2; ++ko)
      aq[ko] = *reinterpret_cast<const bf16x8*>(
          qkv + ((tokbase + qrow) * 3 + 0) * HID + h * HD + ko * 32 + g * 8);
  }

  f32x4 o[4] = {};
  float mrow[4], lrow[4];
#pragma unroll
  for (int r = 0; r < 4; ++r) { mrow[r] = -3.0e38f; lrow[r] = 0.f; }

  const int srowK = lane >> 3;        // 0..7
  const int vkey  = tid >> 2;         // 0..63
  const int vd3   = tid & 3;

  // ---- staging helpers (indices identical to round-4 verified formulas) ----
#define STAGE_K(buf, kb)                                                        \
  {                                                                             \
    _Pragma("unroll")                                                           \
    for (int c = 0; c < 2; ++c) {                                               \
      int seg = w * 2 + c;                                                      \
      int sK  = ((seg >> 1) + srowK) & 7;                                       \
      int srcc = (lane & 7) ^ sK;                                               \
      gld_lds16(qkv + ((tokbase + (kb) + seg * 8 + srowK) * 3 + 1) * HID +      \
                    h * HD + srcc * 8,                                          \
                &Kt[buf][seg * 512]);                                           \
    }                                                                           \
  }

  u16x8 v0n, v1n;
  float mpn[4][4];

  // ---- prologue: stage tile 0 ----
  STAGE_K(0, 0);
  {
    const u16* vp = qkv + ((tokbase + 0 + vkey) * 3 + 2) * HID + h * HD + vd3 * 16;
    v0n = *reinterpret_cast<const u16x8*>(vp);
    v1n = *reinterpret_cast<const u16x8*>(vp + 8);
  }
#pragma unroll
  for (int r = 0; r < 4; ++r) {
    int q = qt * 64 + w * 16 + g * 4 + r;
    const float* mp = mask + ((size_t)b * SEQ + q) * SEQ + 0;
#pragma unroll
    for (int ni = 0; ni < 4; ++ni) mpn[r][ni] = mp[ni * 16 + r16];
  }
#pragma unroll
  for (int j = 0; j < 16; ++j) {
    u16 val = (j < 8) ? (u16)v0n[j] : (u16)v1n[j - 8];
    int row = vd3 * 16 + j;
    int sV  = (vd3 + (j & 7)) & 7;
    Vt[0][row * 64 + (((vkey >> 3) ^ sV) << 3) + (vkey & 7)] = val;
  }
  __syncthreads();   // tile 0 staged (barrier drains vmcnt+lgkm)

#pragma unroll 1
  for (int kb = 0; kb < SEQ; kb += 64) {
    const int cur = (kb >> 6) & 1;
    const int nxt = cur ^ 1;
    const bool more = (kb + 64) < SEQ;

    // consume this tile's mask regs
    float mcur[4][4];
#pragma unroll
    for (int r = 0; r < 4; ++r)
#pragma unroll
      for (int ni = 0; ni < 4; ++ni) mcur[r][ni] = mpn[r][ni];

    // ---- issue next tile's loads (latency hides under compute) ----
    if (more) {
      STAGE_K(nxt, kb + 64);
      const u16* vp = qkv + ((tokbase + kb + 64 + vkey) * 3 + 2) * HID + h * HD + vd3 * 16;
      v0n = *reinterpret_cast<const u16x8*>(vp);
      v1n = *reinterpret_cast<const u16x8*>(vp + 8);
#pragma unroll
      for (int r = 0; r < 4; ++r) {
        int q = qt * 64 + w * 16 + g * 4 + r;
        const float* mp = mask + ((size_t)b * SEQ + q) * SEQ + kb + 64;
#pragma unroll
        for (int ni = 0; ni < 4; ++ni) mpn[r][ni] = mp[ni * 16 + r16];
      }
    }

    // ---- S = Q K^T ----
    f32x4 sf[4] = {};
#pragma unroll
    for (int ko = 0; ko < 2; ++ko) {
      bf16x8 bk[4];
#pragma unroll
      for (int ni = 0; ni < 4; ++ni) {
        int row = ni * 16 + r16;
        int sK  = (ni + (r16 & 7)) & 7;
        bk[ni] = *reinterpret_cast<const bf16x8*>(
            &Kt[cur][row * 64 + (((ko * 4 + g) ^ sK) << 3)]);
      }
#pragma unroll
      for (int ni = 0; ni < 4; ++ni)
        sf[ni] = __builtin_amdgcn_mfma_f32_16x16x32_bf16(aq[ko], bk[ni], sf[ni], 0, 0, 0);
    }

    // ---- online softmax with defer-max (THR=8) ----
    float mx[4];
#pragma unroll
    for (int r = 0; r < 4; ++r) {
      float m_ = -3.0e38f;
#pragma unroll
      for (int ni = 0; ni < 4; ++ni) {
        float sv = sf[ni][r] * 0.125f + mcur[r][ni];
        sf[ni][r] = sv;
        m_ = fmaxf(m_, sv);
      }
      m_ = fmaxf(m_, __shfl_xor(m_, 1));
      m_ = fmaxf(m_, __shfl_xor(m_, 2));
      m_ = fmaxf(m_, __shfl_xor(m_, 4));
      m_ = fmaxf(m_, __shfl_xor(m_, 8));
      mx[r] = m_;
    }
    float need = 0.f;
#pragma unroll
    for (int r = 0; r < 4; ++r) need = fmaxf(need, mx[r] - mrow[r]);
    if (__any(need > 8.0f)) {
#pragma unroll
      for (int r = 0; r < 4; ++r) {
        float mnew  = fmaxf(mrow[r], mx[r]);
        float alpha = __expf(mrow[r] - mnew);
        mrow[r] = mnew;
        lrow[r] *= alpha;
#pragma unroll
        for (int di = 0; di < 4; ++di) o[di][r] *= alpha;
      }
    }
#pragma unroll
    for (int r = 0; r < 4; ++r) {
      float s = 0.f;
#pragma unroll
      for (int ni = 0; ni < 4; ++ni) {
        float p = __expf(sf[ni][r] - mrow[r]);
        sf[ni][r] = p;
        s += p;
      }
      s += __shfl_xor(s, 1); s += __shfl_xor(s, 2);
      s += __shfl_xor(s, 4); s += __shfl_xor(s, 8);
      lrow[r] += s;
      int prow = g * 4 + r;
      int sP   = prow & 7;
#pragma unroll
      for (int ni = 0; ni < 4; ++ni) {
        int chunk = ni * 2 + (r16 >> 3);
        Pl[w][prow * 64 + ((chunk ^ sP) << 3) + (r16 & 7)] = f2bf(sf[ni][r]);
      }
    }
    // no barrier: Pl[w] is wave-private; lgkmcnt orders write->read

    // ---- O += P V ----
#pragma unroll
    for (int kk = 0; kk < 2; ++kk) {
      bf16x8 pa, bv[4];
      pa = *reinterpret_cast<const bf16x8*>(
          &Pl[w][r16 * 64 + (((kk * 4 + g) ^ (r16 & 7)) << 3)]);
#pragma unroll
      for (int di = 0; di < 4; ++di) {
        int row = di * 16 + r16;
        int sV  = (di + (r16 & 7)) & 7;
        bv[di] = *reinterpret_cast<const bf16x8*>(
            &Vt[cur][row * 64 + (((kk * 4 + g) ^ sV) << 3)]);
      }
#pragma unroll
      for (int di = 0; di < 4; ++di)
        o[di] = __builtin_amdgcn_mfma_f32_16x16x32_bf16(pa, bv[di], o[di], 0, 0, 0);
    }

    // ---- write next V tile (loads have had the whole compute to land) ----
    if (more) {
#pragma unroll
      for (int j = 0; j < 16; ++j) {
        u16 val = (j < 8) ? (u16)v0n[j] : (u16)v1n[j - 8];
        int row = vd3 * 16 + j;
        int sV  = (vd3 + (j & 7)) & 7;
        Vt[nxt][row * 64 + (((vkey >> 3) ^ sV) << 3) + (vkey & 7)] = val;
      }
    }
    __syncthreads();   // next tile staged; current-tile reads complete
  }

  // finalize
#pragma unroll
  for (int di = 0; di < 4; ++di)
#pragma unroll
    for (int r = 0; r < 4; ++r) {
      int srow = qt * 64 + w * 16 + g * 4 + r;
      float val = o[di][r] / lrow[r];
      AO[(tokbase + srow) * HID + h * HD + di * 16 + r16] = f2bf(val);
    }
#undef STAGE_K
}

// ---------------- launcher ----------------
extern "C" void kernel_launch(void* const* d_in, const int* in_sizes, int n_in,
                              void* d_out, int out_size, void* d_ws, size_t ws_size,
                              hipStream_t stream) {
  (void)in_sizes; (void)n_in; (void)out_size; (void)ws_size;
  const float* hs   = (const float*)d_in[0];
  const float* mask = (const float*)d_in[1];
  const float* wqkv = (const float*)d_in[2];
  const float* wo   = (const float*)d_in[3];
  float* out = (float*)d_out;

  char* ws   = (char*)d_ws;
  u16* Xb    = (u16*)(ws);                        // 4096x1024  (8 MiB)
  u16* Wqkvb = (u16*)(ws + 8u  * 1024 * 1024);    // 3072x1024  (6 MiB)
  u16* Wob   = (u16*)(ws + 14u * 1024 * 1024);    // 1024x1024  (2 MiB)
  u16* QKVb  = (u16*)(ws + 16u * 1024 * 1024);    // 4096x3072  (24 MiB)
  u16* AOb   = (u16*)(ws + 40u * 1024 * 1024);    // 4096x1024  (8 MiB)

  cvt_kernel<<<4096, 256, 0, stream>>>(hs,   Xb);
  cvt_kernel<<<3072, 256, 0, stream>>>(wqkv, Wqkvb);
  cvt_kernel<<<1024, 256, 0, stream>>>(wo,   Wob);

  gemm_bt<true ><<<dim3(3072 / 128, 4096 / 128), 256, 0, stream>>>(Xb,  Wqkvb, QKVb, NTOK, 3072, HID);
  attn_kernel   <<<1024, 256, 0, stream>>>(QKVb, mask, AOb);
  gemm_bt<false><<<dim3(1024 / 128, 4096 / 128), 256, 0, stream>>>(AOb, Wob,  out,  NTOK, 1024, HID);
}

// Round 6
// 208.522 us; speedup vs baseline: 1.4216x; 1.4216x over previous
//
#include <hip/hip_runtime.h>

typedef unsigned short u16;
using bf16x8 = __attribute__((ext_vector_type(8))) __bf16;
using f32x4  = __attribute__((ext_vector_type(4))) float;
using u16x8  = __attribute__((ext_vector_type(8))) unsigned short;
using u16x4  = __attribute__((ext_vector_type(4))) unsigned short;

#define SEQ   2048
#define HID   1024
#define NHEAD 16
#define HD    64
#define BATCH 2
#define NTOK  4096   // BATCH*SEQ

__device__ __forceinline__ u16 f2bf(float f) {
  unsigned u = __builtin_bit_cast(unsigned, f);
  u += 0x7fffu + ((u >> 16) & 1u);
  return (u16)(u >> 16);
}

__device__ __forceinline__ void gld_lds16(const void* g, void* l) {
  __builtin_amdgcn_global_load_lds(
      (__attribute__((address_space(1))) void*)(__UINTPTR_TYPE__)g,
      (__attribute__((address_space(3))) void*)l, 16, 0, 0);
}

// ---------------- fp32 -> bf16 convert ----------------
__global__ __launch_bounds__(256) void cvt_kernel(const float* __restrict__ in,
                                                  u16* __restrict__ out) {
  int i = (blockIdx.x * 256 + threadIdx.x) * 4;
  float4 v = *reinterpret_cast<const float4*>(in + i);
  u16x4 o = { f2bf(v.x), f2bf(v.y), f2bf(v.z), f2bf(v.w) };
  *reinterpret_cast<u16x4*>(out + i) = o;
}

// ---------------- GEMM: C[M,N] = A[M,K] * B[N,K]^T ---------------- (unchanged)
template<bool BF16OUT>
__global__ __launch_bounds__(256) void gemm_bt(const u16* __restrict__ A,
                                               const u16* __restrict__ B,
                                               void* __restrict__ Cv,
                                               int M, int N, int K) {
  __shared__ u16 At[128 * 64];
  __shared__ u16 Bt[128 * 64];
  const int tid  = threadIdx.x;
  const int wave = tid >> 6;
  const int lane = tid & 63;
  const int g    = lane >> 4;
  const int r16  = lane & 15;
  const int wr   = wave >> 1;
  const int wc   = wave & 1;
  const int bm   = blockIdx.y;
  const int bn   = blockIdx.x;

  const u16* Ab = A + (size_t)bm * 128 * K;
  const u16* Bb = B + (size_t)bn * 128 * K;
  const int srow = lane >> 3;
  const int scol = (lane & 7) * 8;

  f32x4 acc[4][4] = {};

  for (int kt = 0; kt < K; kt += 64) {
#pragma unroll
    for (int c = 0; c < 4; ++c) {
      int seg = wave * 4 + c;
      gld_lds16(Ab + (size_t)(seg * 8 + srow) * K + kt + scol, &At[seg * 512]);
      gld_lds16(Bb + (size_t)(seg * 8 + srow) * K + kt + scol, &Bt[seg * 512]);
    }
    __syncthreads();
#pragma unroll
    for (int ko = 0; ko < 64; ko += 32) {
      bf16x8 af[4], bfr[4];
#pragma unroll
      for (int mi = 0; mi < 4; ++mi)
        af[mi] = *reinterpret_cast<const bf16x8*>(&At[(wr * 64 + mi * 16 + r16) * 64 + ko + g * 8]);
#pragma unroll
      for (int ni = 0; ni < 4; ++ni)
        bfr[ni] = *reinterpret_cast<const bf16x8*>(&Bt[(wc * 64 + ni * 16 + r16) * 64 + ko + g * 8]);
#pragma unroll
      for (int mi = 0; mi < 4; ++mi)
#pragma unroll
        for (int ni = 0; ni < 4; ++ni)
          acc[mi][ni] = __builtin_amdgcn_mfma_f32_16x16x32_bf16(af[mi], bfr[ni], acc[mi][ni], 0, 0, 0);
    }
    __syncthreads();
  }

#pragma unroll
  for (int mi = 0; mi < 4; ++mi)
#pragma unroll
    for (int ni = 0; ni < 4; ++ni) {
      int row0 = bm * 128 + wr * 64 + mi * 16 + g * 4;
      int col  = bn * 128 + wc * 64 + ni * 16 + r16;
#pragma unroll
      for (int r = 0; r < 4; ++r) {
        float v = acc[mi][ni][r];
        if (BF16OUT) ((u16*)Cv)[(size_t)(row0 + r) * N + col] = f2bf(v);
        else         ((float*)Cv)[(size_t)(row0 + r) * N + col] = v;
      }
    }
}

// ---------------- flash attention ----------------
// 1024 blocks (XCD-chunked remap), 4 waves x 16 q-rows; K-tile = 64
// Round-4 structure + K-only double buffer (zero-register global_load_lds
// prefetch issued after P-writes, in flight across PV + next reg loads) and
// no post-P barrier (Pl[w] wave-private). 2 barriers/tile.
// LDS XOR-swizzle on 16B-chunk index: s(row)=((row>>4)+(row&7))&7
__global__ __launch_bounds__(256, 4) void attn_kernel(const u16* __restrict__ qkv,
                                                      const float* __restrict__ mask,
                                                      u16* __restrict__ AO) {
  __shared__ u16 Kt[2][64 * 64];   // [key][d]   swizzled, double-buffered
  __shared__ u16 Vt[64 * 64];      // [d][key]   swizzled (transposed)
  __shared__ u16 Pl[4][16 * 64];   // per-wave P swizzled (wave-private)

  const int tid  = threadIdx.x;
  const int w    = tid >> 6;
  const int lane = tid & 63;
  const int g    = lane >> 4;
  const int r16  = lane & 15;

  const int n  = blockIdx.x;
  const int x  = n & 7;
  const int s_ = n >> 3;
  const int h  = s_ & 15;
  const int t_ = ((s_ >> 4) << 3) + x;
  const int b  = t_ >> 5;
  const int qt = t_ & 31;

  const size_t tokbase = (size_t)b * SEQ;

  bf16x8 aq[2];
  {
    int qrow = qt * 64 + w * 16 + r16;
#pragma unroll
    for (int ko = 0; ko < 2; ++ko)
      aq[ko] = *reinterpret_cast<const bf16x8*>(
          qkv + ((tokbase + qrow) * 3 + 0) * HID + h * HD + ko * 32 + g * 8);
  }

  f32x4 o[4] = {};
  float mrow[4], lrow[4];
#pragma unroll
  for (int r = 0; r < 4; ++r) { mrow[r] = -3.0e38f; lrow[r] = 0.f; }

  const int srowK = lane >> 3;        // 0..7
  const int vkey  = tid >> 2;         // 0..63
  const int vd3   = tid & 3;

#define STAGE_K(buf, kb)                                                        \
  {                                                                             \
    _Pragma("unroll")                                                           \
    for (int c = 0; c < 2; ++c) {                                               \
      int seg = w * 2 + c;                                                      \
      int sK  = ((seg >> 1) + srowK) & 7;                                       \
      int srcc = (lane & 7) ^ sK;                                               \
      gld_lds16(qkv + ((tokbase + (kb) + seg * 8 + srowK) * 3 + 1) * HID +      \
                    h * HD + srcc * 8,                                          \
                &Kt[buf][seg * 512]);                                           \
    }                                                                           \
  }

  // ---- prologue: K tile 0 in flight ----
  STAGE_K(0, 0);

#pragma unroll 1
  for (int kb = 0; kb < SEQ; kb += 64) {
    const int cur = (kb >> 6) & 1;
    const int nxt = cur ^ 1;
    const bool more = (kb + 64) < SEQ;

    // ---- reg loads for THIS tile: mask + V (short live range, R4 position) ----
    float mpre[4][4];
#pragma unroll
    for (int r = 0; r < 4; ++r) {
      int q = qt * 64 + w * 16 + g * 4 + r;
      const float* mp = mask + ((size_t)b * SEQ + q) * SEQ + kb;
#pragma unroll
      for (int ni = 0; ni < 4; ++ni) mpre[r][ni] = mp[ni * 16 + r16];
    }
    const u16* vp = qkv + ((tokbase + kb + vkey) * 3 + 2) * HID + h * HD + vd3 * 16;
    u16x8 v0 = *reinterpret_cast<const u16x8*>(vp);
    u16x8 v1 = *reinterpret_cast<const u16x8*>(vp + 8);

    __syncthreads();   // A: prev-tile LDS reads done; drains vmcnt (Kt[cur], mask, V land)

    // ---- V -> LDS transposed, swizzled scalar writes ----
#pragma unroll
    for (int j = 0; j < 16; ++j) {
      u16 val = (j < 8) ? (u16)v0[j] : (u16)v1[j - 8];
      int row = vd3 * 16 + j;
      int sV  = (vd3 + (j & 7)) & 7;
      Vt[row * 64 + (((vkey >> 3) ^ sV) << 3) + (vkey & 7)] = val;
    }
    __syncthreads();   // B: Vt + Kt[cur] visible to all waves (cheap: vmcnt already 0)

    // ---- S = Q K^T on Kt[cur] ----
    f32x4 sf[4] = {};
#pragma unroll
    for (int ko = 0; ko < 2; ++ko) {
      bf16x8 bk[4];
#pragma unroll
      for (int ni = 0; ni < 4; ++ni) {
        int row = ni * 16 + r16;
        int sK  = (ni + (r16 & 7)) & 7;
        bk[ni] = *reinterpret_cast<const bf16x8*>(
            &Kt[cur][row * 64 + (((ko * 4 + g) ^ sK) << 3)]);
      }
#pragma unroll
      for (int ni = 0; ni < 4; ++ni)
        sf[ni] = __builtin_amdgcn_mfma_f32_16x16x32_bf16(aq[ko], bk[ni], sf[ni], 0, 0, 0);
    }

    // ---- online softmax (rows at g*4+r, cols at r16) ----
#pragma unroll
    for (int r = 0; r < 4; ++r) {
      float mx = -3.0e38f;
#pragma unroll
      for (int ni = 0; ni < 4; ++ni) {
        float sv = sf[ni][r] * 0.125f + mpre[r][ni];
        sf[ni][r] = sv;
        mx = fmaxf(mx, sv);
      }
      mx = fmaxf(mx, __shfl_xor(mx, 1));
      mx = fmaxf(mx, __shfl_xor(mx, 2));
      mx = fmaxf(mx, __shfl_xor(mx, 4));
      mx = fmaxf(mx, __shfl_xor(mx, 8));
      float mnew  = fmaxf(mrow[r], mx);
      float alpha = __expf(mrow[r] - mnew);
      mrow[r] = mnew;
      float s = 0.f;
#pragma unroll
      for (int ni = 0; ni < 4; ++ni) {
        float p = __expf(sf[ni][r] - mnew);
        sf[ni][r] = p;
        s += p;
      }
      s += __shfl_xor(s, 1); s += __shfl_xor(s, 2);
      s += __shfl_xor(s, 4); s += __shfl_xor(s, 8);
      lrow[r] = lrow[r] * alpha + s;
#pragma unroll
      for (int di = 0; di < 4; ++di) o[di][r] *= alpha;
      int prow = g * 4 + r;
      int sP   = prow & 7;
#pragma unroll
      for (int ni = 0; ni < 4; ++ni) {
        int chunk = ni * 2 + (r16 >> 3);
        Pl[w][prow * 64 + ((chunk ^ sP) << 3) + (r16 & 7)] = f2bf(sf[ni][r]);
      }
    }
    // no barrier: Pl[w] is wave-private; lgkmcnt orders write->read

    // ---- prefetch next K tile (zero-register, flies across PV + next loads) ----
    if (more) STAGE_K(nxt, kb + 64);

    // ---- O += P V ----
#pragma unroll
    for (int kk = 0; kk < 2; ++kk) {
      bf16x8 pa, bv[4];
      pa = *reinterpret_cast<const bf16x8*>(
          &Pl[w][r16 * 64 + (((kk * 4 + g) ^ (r16 & 7)) << 3)]);
#pragma unroll
      for (int di = 0; di < 4; ++di) {
        int row = di * 16 + r16;
        int sV  = (di + (r16 & 7)) & 7;
        bv[di] = *reinterpret_cast<const bf16x8*>(
            &Vt[row * 64 + (((kk * 4 + g) ^ sV) << 3)]);
      }
#pragma unroll
      for (int di = 0; di < 4; ++di)
        o[di] = __builtin_amdgcn_mfma_f32_16x16x32_bf16(pa, bv[di], o[di], 0, 0, 0);
    }
  }

  // finalize
#pragma unroll
  for (int di = 0; di < 4; ++di)
#pragma unroll
    for (int r = 0; r < 4; ++r) {
      int srow = qt * 64 + w * 16 + g * 4 + r;
      float val = o[di][r] / lrow[r];
      AO[(tokbase + srow) * HID + h * HD + di * 16 + r16] = f2bf(val);
    }
#undef STAGE_K
}

// ---------------- launcher ----------------
extern "C" void kernel_launch(void* const* d_in, const int* in_sizes, int n_in,
                              void* d_out, int out_size, void* d_ws, size_t ws_size,
                              hipStream_t stream) {
  (void)in_sizes; (void)n_in; (void)out_size; (void)ws_size;
  const float* hs   = (const float*)d_in[0];
  const float* mask = (const float*)d_in[1];
  const float* wqkv = (const float*)d_in[2];
  const float* wo   = (const float*)d_in[3];
  float* out = (float*)d_out;

  char* ws   = (char*)d_ws;
  u16* Xb    = (u16*)(ws);                        // 4096x1024  (8 MiB)
  u16* Wqkvb = (u16*)(ws + 8u  * 1024 * 1024);    // 3072x1024  (6 MiB)
  u16* Wob   = (u16*)(ws + 14u * 1024 * 1024);    // 1024x1024  (2 MiB)
  u16* QKVb  = (u16*)(ws + 16u * 1024 * 1024);    // 4096x3072  (24 MiB)
  u16* AOb   = (u16*)(ws + 40u * 1024 * 1024);    // 4096x1024  (8 MiB)

  cvt_kernel<<<4096, 256, 0, stream>>>(hs,   Xb);
  cvt_kernel<<<3072, 256, 0, stream>>>(wqkv, Wqkvb);
  cvt_kernel<<<1024, 256, 0, stream>>>(wo,   Wob);

  gemm_bt<true ><<<dim3(3072 / 128, 4096 / 128), 256, 0, stream>>>(Xb,  Wqkvb, QKVb, NTOK, 3072, HID);
  attn_kernel   <<<1024, 256, 0, stream>>>(QKVb, mask, AOb);
  gemm_bt<false><<<dim3(1024 / 128, 4096 / 128), 256, 0, stream>>>(AOb, Wob,  out,  NTOK, 1024, HID);
}